// Round 5
// baseline (373.237 us; speedup 1.0000x reference)
//
#include <hip/hip_runtime.h>
#include <stdint.h>

#define S_LEN 512
#define I_DIM 28
#define H_DIM 128
#define O_DIM 28
#define BT    8    // batch rows per block; b-slots 8..15 of fragments are garbage

typedef __attribute__((ext_vector_type(8))) short bf16x8;
typedef __attribute__((ext_vector_type(4))) float f32x4;

static __device__ __forceinline__ short f2bf(float f) {   // cold paths only
    unsigned u = __float_as_uint(f);
    u = (u + 0x7fffu + ((u >> 16) & 1u)) >> 16;
    return (short)u;
}
static __device__ __forceinline__ float bf2f(unsigned short u) {
    return __uint_as_float(((unsigned)u) << 16);
}
static __device__ __forceinline__ unsigned cvt_pk(float a, float b) {
    unsigned r;
    asm("v_cvt_pk_bf16_f32 %0, %1, %2" : "=v"(r) : "v"(a), "v"(b));
    return r;
}
// tanh(a) = 1 - 2/(1+e^{2a}) : 2 trans + 3 VALU
#define TWO_LOG2E 2.8853900817779268f
static __device__ __forceinline__ float fast_tanh(float a) {
    float e = __builtin_amdgcn_exp2f(a * TWO_LOG2E);
    float r = __builtin_amdgcn_rcpf(1.0f + e);
    return fmaf(-2.0f, r, 1.0f);
}

__global__ __launch_bounds__(128, 1) void rnn_fused(
    const float* __restrict__ x,
    const float* __restrict__ W_ih, const float* __restrict__ b_ih,
    const float* __restrict__ W_hh, const float* __restrict__ b_hh,
    const float* __restrict__ W_ho, const float* __restrict__ b_ho,
    float* __restrict__ out)
{
    const int tid  = threadIdx.x;
    const int wave = tid >> 6;         // 0..1 -> j-cols [64w, 64w+64)
    const int lane = tid & 63;
    const int l15  = lane & 15;        // b-col slot (valid < 8)
    const int lk   = lane >> 4;        // 0..3 k-group
    const int r0   = blockIdx.x * BT;

    // h^T as B-fragments: [buf][k-chunk kc][lane] ; chunk kc holds k=j in [32kc,32kc+32)
    __shared__ __align__(16) bf16x8 hx[2][4][64];   // 8 KB
    __shared__ __align__(16) bf16x8 xring[8][64];   // 8 KB

    // ---- stationary A-fragments (swapped form). Tile T = 4*wave + tt, j = T*16 + m.
    // A-frag: lane(l15,lk) holds A[m=l15][k=lk*8+e]. C^T: reg r -> j = T*16 + lk*4 + r, col b = l15.
    bf16x8 Ahh[4][4];   // [tt][kc]
    bf16x8 Aih[4];
    f32x4  biasv[4];
    #pragma unroll
    for (int tt = 0; tt < 4; ++tt) {
        const int T  = 4 * wave + tt;
        const int jA = T * 16 + l15;
        #pragma unroll
        for (int kc = 0; kc < 4; ++kc)
            #pragma unroll
            for (int e = 0; e < 8; ++e)
                Ahh[tt][kc][e] = f2bf(W_hh[(kc * 32 + lk * 8 + e) * H_DIM + jA]);
        #pragma unroll
        for (int e = 0; e < 8; ++e) {
            int i = lk * 8 + e;
            Aih[tt][e] = (i < I_DIM) ? f2bf(W_ih[i * H_DIM + jA]) : (short)0;
        }
        #pragma unroll
        for (int r = 0; r < 4; ++r) {
            int jC = T * 16 + lk * 4 + r;
            biasv[tt][r] = b_ih[jC] + b_hh[jC];
        }
    }

    // write byte offsets: tile T's (j = T*16+lk*4+{0..3}, b=l15) -> B-frag slot of chunk T>>1
    int wb_off[4];
    #pragma unroll
    for (int tt = 0; tt < 4; ++tt) {
        const int T = 4 * wave + tt;
        wb_off[tt] = (T >> 1) * 1024 + ((T & 1) * 2 + (lk >> 1)) * 256
                   + l15 * 16 + (lk & 1) * 8;
    }

    // h0 = 0 (all slots incl. garbage)
    for (int i = tid; i < 256; i += 128) {
        bf16x8 z = {0,0,0,0,0,0,0,0};
        (&hx[0][0][0])[i] = z;
    }

    const bool hasHi = (lk < 3);       // k-group 3: only i=24..27 valid
    // x rows: clamp duplicate for garbage slots (keeps loads uniform, L2 absorbs)
    const float* xbase = x + (size_t)(r0 + (l15 & 7)) * S_LEN * I_DIM + lk * 8;

    // ---- prologue: wave w stages frames 2w, 2w+1 ----
    #pragma unroll
    for (int q = 0; q < 2; ++q) {
        const int f = 2 * wave + q;
        const float* src = xbase + f * I_DIM;
        float4 lo = *(const float4*)src;
        float4 hi = hasHi ? *(const float4*)(src + 4) : make_float4(0.f,0.f,0.f,0.f);
        union { bf16x8 v; unsigned u[4]; } fr;
        fr.u[0] = cvt_pk(lo.x, lo.y); fr.u[1] = cvt_pk(lo.z, lo.w);
        fr.u[2] = cvt_pk(hi.x, hi.y); fr.u[3] = cvt_pk(hi.z, hi.w);
        xring[f][lane] = fr.v;
    }
    asm volatile("s_waitcnt lgkmcnt(0)" ::: "memory");
    __builtin_amdgcn_s_barrier();
    asm volatile("" ::: "memory");

    // ---- time loop: groups of 4 steps ----
    for (int t4 = 0; t4 < S_LEN; t4 += 4) {
        // prefetch 2 frames per wave for the NEXT group
        const int f0 = t4 + 4 + 2 * wave;
        const bool doPf = (f0 < S_LEN);
        float4 aLo = make_float4(0.f,0.f,0.f,0.f), aHi = aLo, bLo = aLo, bHi = aLo;
        if (doPf) {
            const float* s0 = xbase + (size_t)f0 * I_DIM;
            const float* s1 = s0 + I_DIM;
            aLo = *(const float4*)s0;
            bLo = *(const float4*)s1;
            if (hasHi) { aHi = *(const float4*)(s0 + 4); bHi = *(const float4*)(s1 + 4); }
        }

        #pragma unroll
        for (int p = 0; p < 4; ++p) {
            const int t = t4 + p;
            const bf16x8* rb = &hx[t & 1][0][0];
            char* wbuf = (char*)&hx[(t & 1) ^ 1][0][0];

            // state + x reads first (latency)
            bf16x8 b0 = rb[0 * 64 + lane];
            bf16x8 b1 = rb[1 * 64 + lane];
            bf16x8 b2 = rb[2 * 64 + lane];
            bf16x8 b3 = rb[3 * 64 + lane];
            bf16x8 xcur = xring[t & 7][lane];

            // 4 tiles x 2 independent chains (depth 3 + 2)
            f32x4 s[4];
            #pragma unroll
            for (int tt = 0; tt < 4; ++tt) {
                f32x4 a = biasv[tt];
                a = __builtin_amdgcn_mfma_f32_16x16x32_bf16(Aih[tt],    xcur, a, 0,0,0);
                a = __builtin_amdgcn_mfma_f32_16x16x32_bf16(Ahh[tt][0], b0,   a, 0,0,0);
                a = __builtin_amdgcn_mfma_f32_16x16x32_bf16(Ahh[tt][1], b1,   a, 0,0,0);
                f32x4 c = {0.f,0.f,0.f,0.f};
                c = __builtin_amdgcn_mfma_f32_16x16x32_bf16(Ahh[tt][2], b2,   c, 0,0,0);
                c = __builtin_amdgcn_mfma_f32_16x16x32_bf16(Ahh[tt][3], b3,   c, 0,0,0);
                s[tt] = a + c;
            }

            if (p == 2 && doPf) {                   // late ring writes of prefetch
                union { bf16x8 v; unsigned u[4]; } fa, fb;
                fa.u[0] = cvt_pk(aLo.x, aLo.y); fa.u[1] = cvt_pk(aLo.z, aLo.w);
                fa.u[2] = cvt_pk(aHi.x, aHi.y); fa.u[3] = cvt_pk(aHi.z, aHi.w);
                fb.u[0] = cvt_pk(bLo.x, bLo.y); fb.u[1] = cvt_pk(bLo.z, bLo.w);
                fb.u[2] = cvt_pk(bHi.x, bHi.y); fb.u[3] = cvt_pk(bHi.z, bHi.w);
                xring[f0 & 7][lane]       = fa.v;
                xring[(f0 + 1) & 7][lane] = fb.v;
            }

            // merge tile pairs: lanes bit3=0 do tile 2q (b=l15), bit3=1 do tile 2q+1 (b=l15-8)
            #pragma unroll
            for (int q = 0; q < 2; ++q) {
                float h[4], hb[4];
                #pragma unroll
                for (int r = 0; r < 4; ++r) {
                    float sa  = s[2 * q][r];
                    float sbs = __shfl_xor(s[2 * q + 1][r], 8, 64);
                    float mv  = ((lane & 8) == 0) ? sa : sbs;
                    float hv  = fast_tanh(mv);
                    h[r]  = hv;
                    hb[r] = __shfl_xor(hv, 8, 64);
                }
                uint2 wA, wB;
                wA.x = cvt_pk(h[0],  h[1]);  wA.y = cvt_pk(h[2],  h[3]);
                wB.x = cvt_pk(hb[0], hb[1]); wB.y = cvt_pk(hb[2], hb[3]);
                *(uint2*)(wbuf + wb_off[2 * q])     = wA;
                *(uint2*)(wbuf + wb_off[2 * q + 1]) = wB;
            }

            asm volatile("s_waitcnt lgkmcnt(0)" ::: "memory");
            __builtin_amdgcn_s_barrier();
            asm volatile("" ::: "memory");
        }
    }

    // ---- epilogue: out = h_512 @ W_ho + b_ho ; final h in hx[0] ----
    // h[b][j] at chunk j>>5, lane ((j&31)>>3)*16 + b, halfword j&7
    for (int idx = tid; idx < BT * O_DIM; idx += 128) {
        const int b = idx / O_DIM;
        const int o = idx - b * O_DIM;
        float sum = b_ho[o];
        const unsigned short* hb = (const unsigned short*)&hx[0][0][0];
        #pragma unroll 4
        for (int j = 0; j < H_DIM; ++j) {
            int slot = (j >> 5) * 64 + ((j & 31) >> 3) * 16 + b;
            sum += bf2f(hb[slot * 8 + (j & 7)]) * W_ho[j * O_DIM + o];
        }
        out[(size_t)(r0 + b) * O_DIM + o] = sum;
    }
}

extern "C" void kernel_launch(void* const* d_in, const int* in_sizes, int n_in,
                              void* d_out, int out_size, void* d_ws, size_t ws_size,
                              hipStream_t stream) {
    const float* x    = (const float*)d_in[0];
    const float* W_ih = (const float*)d_in[1];
    const float* b_ih = (const float*)d_in[2];
    const float* W_hh = (const float*)d_in[3];
    const float* b_hh = (const float*)d_in[4];
    const float* W_ho = (const float*)d_in[5];
    const float* b_ho = (const float*)d_in[6];
    const int B = in_sizes[0] / (S_LEN * I_DIM);   // 4096
    rnn_fused<<<B / BT, 128, 0, stream>>>(x, W_ih, b_ih, W_hh, b_hh, W_ho, b_ho,
                                          (float*)d_out);
}

// Round 6
// 314.077 us; speedup vs baseline: 1.1884x; 1.1884x over previous
//
#include <hip/hip_runtime.h>
#include <stdint.h>

#define S_LEN 512
#define I_DIM 28
#define H_DIM 128
#define O_DIM 28
#define BT    16   // batch rows per block

typedef __attribute__((ext_vector_type(8))) short bf16x8;
typedef __attribute__((ext_vector_type(4))) float f32x4;

static __device__ __forceinline__ short f2bf(float f) {   // cold paths only
    unsigned u = __float_as_uint(f);
    u = (u + 0x7fffu + ((u >> 16) & 1u)) >> 16;
    return (short)u;
}
static __device__ __forceinline__ float bf2f(unsigned short u) {
    return __uint_as_float(((unsigned)u) << 16);
}
static __device__ __forceinline__ unsigned cvt_pk(float a, float b) {
    unsigned r;
    asm("v_cvt_pk_bf16_f32 %0, %1, %2" : "=v"(r) : "v"(a), "v"(b));
    return r;
}
// tanh(a) = 1 - 2/(1+e^{2a}) : 2 trans + 3 VALU (validated R1-R5)
#define TWO_LOG2E 2.8853900817779268f
static __device__ __forceinline__ float fast_tanh(float a) {
    float e = __builtin_amdgcn_exp2f(a * TWO_LOG2E);
    float r = __builtin_amdgcn_rcpf(1.0f + e);
    return fmaf(-2.0f, r, 1.0f);
}

__global__ __launch_bounds__(256, 1) void rnn_fused(
    const float* __restrict__ x,
    const float* __restrict__ W_ih, const float* __restrict__ b_ih,
    const float* __restrict__ W_hh, const float* __restrict__ b_hh,
    const float* __restrict__ W_ho, const float* __restrict__ b_ho,
    float* __restrict__ out)
{
    const int tid  = threadIdx.x;
    const int wave = tid >> 6;         // 0..3 -> owns h-chunk k in [32w, 32w+32)
    const int lane = tid & 63;
    const int l15  = lane & 15;        // batch-row slot
    const int lk   = lane >> 4;        // 0..3 k-group
    const int r0   = blockIdx.x * BT;

    // h^T B-fragments, double buffered: hx[buf][chunk][lane]. 8 KB total.
    __shared__ __align__(16) bf16x8 hx[2][4][64];

    // ---- stationary A-fragments (swapped form C^T = W^T h^T) ----
    // Wave w computes tiles A,B covering j in [32w,32w+32):
    //   tile A: lane(lk,l15) reg r -> j = 32w + 8lk + r     (B-frag elems 0-3)
    //   tile B: lane(lk,l15) reg r -> j = 32w + 8lk + 4 + r (B-frag elems 4-7)
    // A-frag load: lane(lk,l15) elem e holds W[k=8lk+e][j(m=l15)],
    //   j(m) = 32w + 8*(m>>2) + (m&3) (+4 for tile B).
    bf16x8 Ahh[2][4];   // [tile][k-chunk]
    bf16x8 Aih[2];
    f32x4  biasv[2];
    const int jmA = 32 * wave + ((l15 >> 2) << 3) + (l15 & 3);
    #pragma unroll
    for (int T = 0; T < 2; ++T) {
        const int jA = jmA + T * 4;
        #pragma unroll
        for (int kc = 0; kc < 4; ++kc)
            #pragma unroll
            for (int e = 0; e < 8; ++e)
                Ahh[T][kc][e] = f2bf(W_hh[(kc * 32 + lk * 8 + e) * H_DIM + jA]);
        #pragma unroll
        for (int e = 0; e < 8; ++e) {
            int i = lk * 8 + e;
            Aih[T][e] = (i < I_DIM) ? f2bf(W_ih[i * H_DIM + jA]) : (short)0;
        }
        #pragma unroll
        for (int r = 0; r < 4; ++r) {
            int jC = 32 * wave + lk * 8 + T * 4 + r;
            biasv[T][r] = b_ih[jC] + b_hh[jC];
        }
    }

    // h0 = 0
    {
        bf16x8 z = {0,0,0,0,0,0,0,0};
        hx[0][0][tid >> 6 == wave ? 0 : 0]; // no-op guard against DCE confusion
        (&hx[0][0][0])[tid] = z;
    }

    const bool hasHi = (lk < 3);       // k-group 3: only i=24..27 valid
    const float* xrow = x + (size_t)(r0 + l15) * S_LEN * I_DIM + lk * 8;

    // x register pipeline: two 4-frame buffers, 8 steps deep.
    float4 aLo0, aHi0, aLo1, aHi1, aLo2, aHi2, aLo3, aHi3;   // bufA
    float4 bLo0, bHi0, bLo1, bHi1, bLo2, bHi2, bLo3, bHi3;   // bufB
    float4 z4 = make_float4(0.f, 0.f, 0.f, 0.f);

#define ISSUE_BUF(Lo0,Hi0,Lo1,Hi1,Lo2,Hi2,Lo3,Hi3, F)                          \
    {                                                                          \
        int f0_ = (F)     < S_LEN ? (F)     : S_LEN - 4;                       \
        int f1_ = (F) + 1 < S_LEN ? (F) + 1 : S_LEN - 4;                       \
        int f2_ = (F) + 2 < S_LEN ? (F) + 2 : S_LEN - 4;                       \
        int f3_ = (F) + 3 < S_LEN ? (F) + 3 : S_LEN - 4;                       \
        Lo0 = *(const float4*)(xrow + (size_t)f0_ * I_DIM);                    \
        Hi0 = hasHi ? *(const float4*)(xrow + (size_t)f0_ * I_DIM + 4) : z4;   \
        Lo1 = *(const float4*)(xrow + (size_t)f1_ * I_DIM);                    \
        Hi1 = hasHi ? *(const float4*)(xrow + (size_t)f1_ * I_DIM + 4) : z4;   \
        Lo2 = *(const float4*)(xrow + (size_t)f2_ * I_DIM);                    \
        Hi2 = hasHi ? *(const float4*)(xrow + (size_t)f2_ * I_DIM + 4) : z4;   \
        Lo3 = *(const float4*)(xrow + (size_t)f3_ * I_DIM);                    \
        Hi3 = hasHi ? *(const float4*)(xrow + (size_t)f3_ * I_DIM + 4) : z4;   \
    }

#define CVT_FRAGS(Lo0,Hi0,Lo1,Hi1,Lo2,Hi2,Lo3,Hi3)                             \
    {                                                                          \
        union { bf16x8 v; unsigned u[4]; } fr_;                                \
        fr_.u[0] = cvt_pk(Lo0.x, Lo0.y); fr_.u[1] = cvt_pk(Lo0.z, Lo0.w);      \
        fr_.u[2] = cvt_pk(Hi0.x, Hi0.y); fr_.u[3] = cvt_pk(Hi0.z, Hi0.w);      \
        xf0 = fr_.v;                                                           \
        fr_.u[0] = cvt_pk(Lo1.x, Lo1.y); fr_.u[1] = cvt_pk(Lo1.z, Lo1.w);      \
        fr_.u[2] = cvt_pk(Hi1.x, Hi1.y); fr_.u[3] = cvt_pk(Hi1.z, Hi1.w);      \
        xf1 = fr_.v;                                                           \
        fr_.u[0] = cvt_pk(Lo2.x, Lo2.y); fr_.u[1] = cvt_pk(Lo2.z, Lo2.w);      \
        fr_.u[2] = cvt_pk(Hi2.x, Hi2.y); fr_.u[3] = cvt_pk(Hi2.z, Hi2.w);      \
        xf2 = fr_.v;                                                           \
        fr_.u[0] = cvt_pk(Lo3.x, Lo3.y); fr_.u[1] = cvt_pk(Lo3.z, Lo3.w);      \
        fr_.u[2] = cvt_pk(Hi3.x, Hi3.y); fr_.u[3] = cvt_pk(Hi3.z, Hi3.w);      \
        xf3 = fr_.v;                                                           \
    }

// One RNN step. PAR = t&1 (compile-time), XF = x fragment register.
#define STEP(PAR, XF)                                                          \
    {                                                                          \
        bf16x8 b0 = hx[PAR][0][lane];                                          \
        bf16x8 b1 = hx[PAR][1][lane];                                          \
        bf16x8 b2 = hx[PAR][2][lane];                                          \
        bf16x8 b3 = hx[PAR][3][lane];                                          \
        f32x4 aA = biasv[0], aB = biasv[1];                                    \
        f32x4 cA = {0.f,0.f,0.f,0.f}, cB = {0.f,0.f,0.f,0.f};                  \
        aA = __builtin_amdgcn_mfma_f32_16x16x32_bf16(Aih[0],    XF, aA, 0,0,0);\
        aB = __builtin_amdgcn_mfma_f32_16x16x32_bf16(Aih[1],    XF, aB, 0,0,0);\
        aA = __builtin_amdgcn_mfma_f32_16x16x32_bf16(Ahh[0][0], b0, aA, 0,0,0);\
        aB = __builtin_amdgcn_mfma_f32_16x16x32_bf16(Ahh[1][0], b0, aB, 0,0,0);\
        aA = __builtin_amdgcn_mfma_f32_16x16x32_bf16(Ahh[0][1], b1, aA, 0,0,0);\
        aB = __builtin_amdgcn_mfma_f32_16x16x32_bf16(Ahh[1][1], b1, aB, 0,0,0);\
        cA = __builtin_amdgcn_mfma_f32_16x16x32_bf16(Ahh[0][2], b2, cA, 0,0,0);\
        cB = __builtin_amdgcn_mfma_f32_16x16x32_bf16(Ahh[1][2], b2, cB, 0,0,0);\
        cA = __builtin_amdgcn_mfma_f32_16x16x32_bf16(Ahh[0][3], b3, cA, 0,0,0);\
        cB = __builtin_amdgcn_mfma_f32_16x16x32_bf16(Ahh[1][3], b3, cB, 0,0,0);\
        f32x4 sA = aA + cA, sB = aB + cB;                                      \
        float h0_ = fast_tanh(sA[0]), h1_ = fast_tanh(sA[1]);                  \
        float h2_ = fast_tanh(sA[2]), h3_ = fast_tanh(sA[3]);                  \
        float h4_ = fast_tanh(sB[0]), h5_ = fast_tanh(sB[1]);                  \
        float h6_ = fast_tanh(sB[2]), h7_ = fast_tanh(sB[3]);                  \
        union { bf16x8 v; unsigned u[4]; } hf_;                                \
        hf_.u[0] = cvt_pk(h0_, h1_); hf_.u[1] = cvt_pk(h2_, h3_);              \
        hf_.u[2] = cvt_pk(h4_, h5_); hf_.u[3] = cvt_pk(h6_, h7_);              \
        hx[(PAR) ^ 1][wave][lane] = hf_.v;                                     \
        asm volatile("s_waitcnt lgkmcnt(0)" ::: "memory");                     \
        __builtin_amdgcn_s_barrier();                                          \
        asm volatile("" ::: "memory");                                        \
    }

    // prologue: fill both x pipeline buffers (frames 0-3, 4-7)
    ISSUE_BUF(aLo0,aHi0,aLo1,aHi1,aLo2,aHi2,aLo3,aHi3, 0)
    ISSUE_BUF(bLo0,bHi0,bLo1,bHi1,bLo2,bHi2,bLo3,bHi3, 4)

    asm volatile("s_waitcnt lgkmcnt(0)" ::: "memory");
    __builtin_amdgcn_s_barrier();
    asm volatile("" ::: "memory");

    bf16x8 xf0, xf1, xf2, xf3;

    for (int t8 = 0; t8 < S_LEN; t8 += 8) {
        // half 0: steps t8..t8+3 use bufA (loaded 8 steps ago); reissue bufA
        CVT_FRAGS(aLo0,aHi0,aLo1,aHi1,aLo2,aHi2,aLo3,aHi3)
        ISSUE_BUF(aLo0,aHi0,aLo1,aHi1,aLo2,aHi2,aLo3,aHi3, t8 + 8)
        STEP(0, xf0)
        STEP(1, xf1)
        STEP(0, xf2)
        STEP(1, xf3)
        // half 1: steps t8+4..t8+7 use bufB; reissue bufB
        CVT_FRAGS(bLo0,bHi0,bLo1,bHi1,bLo2,bHi2,bLo3,bHi3)
        ISSUE_BUF(bLo0,bHi0,bLo1,bHi1,bLo2,bHi2,bLo3,bHi3, t8 + 12)
        STEP(0, xf0)
        STEP(1, xf1)
        STEP(0, xf2)
        STEP(1, xf3)
    }

    // ---- epilogue: out = h_512 @ W_ho + b_ho ; final h in hx[0] ----
    // h[b][j]: chunk j>>5, lane ((j&31)>>3)*16 + b, halfword j&7
    for (int idx = tid; idx < BT * O_DIM; idx += 256) {
        const int b = idx / O_DIM;
        const int o = idx - b * O_DIM;
        float sum = b_ho[o];
        const unsigned short* hb = (const unsigned short*)&hx[0][0][0];
        #pragma unroll 4
        for (int j = 0; j < H_DIM; ++j) {
            int slot = (j >> 5) * 64 + ((j & 31) >> 3) * 16 + b;
            sum += bf2f(hb[slot * 8 + (j & 7)]) * W_ho[j * O_DIM + o];
        }
        out[(size_t)(r0 + b) * O_DIM + o] = sum;
    }
#undef STEP
#undef CVT_FRAGS
#undef ISSUE_BUF
}

extern "C" void kernel_launch(void* const* d_in, const int* in_sizes, int n_in,
                              void* d_out, int out_size, void* d_ws, size_t ws_size,
                              hipStream_t stream) {
    const float* x    = (const float*)d_in[0];
    const float* W_ih = (const float*)d_in[1];
    const float* b_ih = (const float*)d_in[2];
    const float* W_hh = (const float*)d_in[3];
    const float* b_hh = (const float*)d_in[4];
    const float* W_ho = (const float*)d_in[5];
    const float* b_ho = (const float*)d_in[6];
    const int B = in_sizes[0] / (S_LEN * I_DIM);   // 4096
    rnn_fused<<<B / BT, 256, 0, stream>>>(x, W_ih, b_ih, W_hh, b_hh, W_ho, b_ho,
                                          (float*)d_out);
}

// Round 7
// 187.177 us; speedup vs baseline: 1.9940x; 1.6780x over previous
//
#include <hip/hip_runtime.h>
#include <stdint.h>

#define S_LEN 512
#define I_DIM 28
#define H_DIM 128
#define O_DIM 28
#define BT    16   // batch rows per block

typedef __attribute__((ext_vector_type(8))) short bf16x8;
typedef __attribute__((ext_vector_type(4))) float f32x4;

static __device__ __forceinline__ short f2bf(float f) {   // cold paths only
    unsigned u = __float_as_uint(f);
    u = (u + 0x7fffu + ((u >> 16) & 1u)) >> 16;
    return (short)u;
}
static __device__ __forceinline__ float bf2f(unsigned short u) {
    return __uint_as_float(((unsigned)u) << 16);
}
static __device__ __forceinline__ unsigned cvt_pk(float a, float b) {
    unsigned r;
    asm("v_cvt_pk_bf16_f32 %0, %1, %2" : "=v"(r) : "v"(a), "v"(b));
    return r;
}
// tanh(a) = 1 - 2/(1+e^{2a}) : 2 trans + 3 VALU (validated R1-R6)
#define TWO_LOG2E 2.8853900817779268f
static __device__ __forceinline__ float fast_tanh(float a) {
    float e = __builtin_amdgcn_exp2f(a * TWO_LOG2E);
    float r = __builtin_amdgcn_rcpf(1.0f + e);
    return fmaf(-2.0f, r, 1.0f);
}

__global__ __launch_bounds__(256, 1) void rnn_fused(
    const float* __restrict__ x,
    const float* __restrict__ W_ih, const float* __restrict__ b_ih,
    const float* __restrict__ W_hh, const float* __restrict__ b_hh,
    const float* __restrict__ W_ho, const float* __restrict__ b_ho,
    float* __restrict__ out)
{
    const int tid  = threadIdx.x;
    const int wave = tid >> 6;         // 0..3 -> owns h-chunk wave (cols 32w..32w+31)
    const int lane = tid & 63;
    const int l15  = lane & 15;        // batch-row slot
    const int lk   = lane >> 4;        // 0..3 k-group
    const int r0   = blockIdx.x * BT;

    // h^T B-fragments by chunk, double buffered (8 KB); x B-frag ring (8 KB)
    __shared__ __align__(16) bf16x8 hx[2][4][64];
    __shared__ __align__(16) bf16x8 xring[8][64];

    // ---- stationary A-fragments, wave-RELATIVE chunk order (rule #20: all
    // hot-loop indices compile-time). Arel[T][q] = W_hh chunk (wave+q)&3.
    // Tile T covers j(m) = 32w + 8*(m>>2) + 4T + (m&3); C reg r -> j = 32w+8lk+4T+r.
    bf16x8 Arel[2][4];
    bf16x8 Aih[2];
    f32x4  biasv[2];
    const int jmA = 32 * wave + ((l15 >> 2) << 3) + (l15 & 3);
    #pragma unroll
    for (int T = 0; T < 2; ++T) {
        const int jA = jmA + 4 * T;
        #pragma unroll
        for (int q = 0; q < 4; ++q) {
            const int kc = (wave + q) & 3;
            #pragma unroll
            for (int e = 0; e < 8; ++e)
                Arel[T][q][e] = f2bf(W_hh[(kc * 32 + lk * 8 + e) * H_DIM + jA]);
        }
        #pragma unroll
        for (int e = 0; e < 8; ++e) {
            int i = lk * 8 + e;
            Aih[T][e] = (i < I_DIM) ? f2bf(W_ih[i * H_DIM + jA]) : (short)0;
        }
        #pragma unroll
        for (int r = 0; r < 4; ++r) {
            int jC = 32 * wave + lk * 8 + 4 * T + r;
            biasv[T][r] = b_ih[jC] + b_hh[jC];
        }
    }

    // foreign-chunk LDS slot offsets (elements into hx[par])
    const int o1 = ((wave + 1) & 3) * 64 + lane;
    const int o2 = ((wave + 2) & 3) * 64 + lane;
    const int o3 = ((wave + 3) & 3) * 64 + lane;

    // h0 = 0: each wave zeroes its chunk in LDS and its register copy
    bf16x8 bown = {0,0,0,0,0,0,0,0};
    hx[0][wave][lane] = bown;

    const bool hasHi = (lk < 3);       // k-group 3: only i=24..27 valid
    const float* xbase = x + (size_t)(r0 + l15) * S_LEN * I_DIM + lk * 8;

    // ---- prologue: wave w stages x frame w (frames 0..3) ----
    {
        const float* src = xbase + wave * I_DIM;
        float4 lo = *(const float4*)src;
        float4 hi = hasHi ? *(const float4*)(src + 4) : make_float4(0.f,0.f,0.f,0.f);
        union { bf16x8 v; unsigned u[4]; } fr;
        fr.u[0] = cvt_pk(lo.x, lo.y); fr.u[1] = cvt_pk(lo.z, lo.w);
        fr.u[2] = cvt_pk(hi.x, hi.y); fr.u[3] = cvt_pk(hi.z, hi.w);
        xring[wave][lane] = fr.v;
    }
    asm volatile("s_waitcnt lgkmcnt(0)" ::: "memory");
    __builtin_amdgcn_s_barrier();
    asm volatile("" ::: "memory");

    bf16x8 xcur = xring[0][lane];

// One step. PAR/P compile-time. Reads foreign chunks + next x-frag first,
// covers their latency with reg-only MFMAs (x + own chunk), consumes foreign
// chunks in arrival order (compiler inserts counted lgkmcnt), then tanh+pack
// (lane-local: C output IS next step's B-frag), one b128 write, drain, barrier.
#define RSTEP(PAR, P)                                                          \
    {                                                                          \
        const bf16x8* hxp = &hx[PAR][0][0];                                    \
        bf16x8 g1 = hxp[o1];                                                   \
        bf16x8 g2 = hxp[o2];                                                   \
        bf16x8 g3 = hxp[o3];                                                   \
        bf16x8 xnext = xring[(t4 + P + 1) & 7][lane];                          \
        if (P == 0 && tf < S_LEN) {                                            \
            const float* src = xbase + (size_t)tf * I_DIM;                     \
            pf_lo = *(const float4*)src;                                       \
            if (hasHi) pf_hi = *(const float4*)(src + 4);                      \
        }                                                                      \
        f32x4 a0 = biasv[0], a1 = biasv[1];                                    \
        a0 = __builtin_amdgcn_mfma_f32_16x16x32_bf16(Aih[0],     xcur, a0, 0,0,0); \
        a1 = __builtin_amdgcn_mfma_f32_16x16x32_bf16(Aih[1],     xcur, a1, 0,0,0); \
        a0 = __builtin_amdgcn_mfma_f32_16x16x32_bf16(Arel[0][0], bown, a0, 0,0,0); \
        a1 = __builtin_amdgcn_mfma_f32_16x16x32_bf16(Arel[1][0], bown, a1, 0,0,0); \
        f32x4 c0 = {0.f,0.f,0.f,0.f}, c1 = {0.f,0.f,0.f,0.f};                  \
        c0 = __builtin_amdgcn_mfma_f32_16x16x32_bf16(Arel[0][1], g1, c0, 0,0,0); \
        c1 = __builtin_amdgcn_mfma_f32_16x16x32_bf16(Arel[1][1], g1, c1, 0,0,0); \
        a0 = __builtin_amdgcn_mfma_f32_16x16x32_bf16(Arel[0][2], g2, a0, 0,0,0); \
        a1 = __builtin_amdgcn_mfma_f32_16x16x32_bf16(Arel[1][2], g2, a1, 0,0,0); \
        c0 = __builtin_amdgcn_mfma_f32_16x16x32_bf16(Arel[0][3], g3, c0, 0,0,0); \
        c1 = __builtin_amdgcn_mfma_f32_16x16x32_bf16(Arel[1][3], g3, c1, 0,0,0); \
        if (P == 2 && tf < S_LEN) {                                            \
            union { bf16x8 v; unsigned u[4]; } fr;                             \
            fr.u[0] = cvt_pk(pf_lo.x, pf_lo.y); fr.u[1] = cvt_pk(pf_lo.z, pf_lo.w); \
            fr.u[2] = cvt_pk(pf_hi.x, pf_hi.y); fr.u[3] = cvt_pk(pf_hi.z, pf_hi.w); \
            xring[tf & 7][lane] = fr.v;                                        \
        }                                                                      \
        f32x4 s0 = a0 + c0, s1 = a1 + c1;                                      \
        float h0_ = fast_tanh(s0[0]), h1_ = fast_tanh(s0[1]);                  \
        float h2_ = fast_tanh(s0[2]), h3_ = fast_tanh(s0[3]);                  \
        float h4_ = fast_tanh(s1[0]), h5_ = fast_tanh(s1[1]);                  \
        float h6_ = fast_tanh(s1[2]), h7_ = fast_tanh(s1[3]);                  \
        union { bf16x8 v; unsigned u[4]; } hf;                                 \
        hf.u[0] = cvt_pk(h0_, h1_); hf.u[1] = cvt_pk(h2_, h3_);                \
        hf.u[2] = cvt_pk(h4_, h5_); hf.u[3] = cvt_pk(h6_, h7_);                \
        hx[(PAR) ^ 1][wave][lane] = hf.v;                                      \
        bown = hf.v;                                                           \
        asm volatile("s_waitcnt lgkmcnt(0)" ::: "memory");                     \
        __builtin_amdgcn_s_barrier();                                          \
        asm volatile("" ::: "memory");                                        \
        xcur = xnext;                                                          \
    }

    for (int t4 = 0; t4 < S_LEN; t4 += 4) {
        const int tf = t4 + 4 + wave;              // x frame this wave stages
        float4 pf_lo = make_float4(0.f,0.f,0.f,0.f), pf_hi = pf_lo;
        RSTEP(0, 0)
        RSTEP(1, 1)
        RSTEP(0, 2)
        RSTEP(1, 3)
    }
#undef RSTEP

    // ---- epilogue: out = h_512 @ W_ho + b_ho ; final h in hx[0] ----
    // h[b][j]: chunk j>>5, lane ((j>>3)&3)*16 + b, halfword j&7
    for (int idx = tid; idx < BT * O_DIM; idx += 256) {
        const int b = idx / O_DIM;
        const int o = idx - b * O_DIM;
        float sum = b_ho[o];
        const unsigned short* hb = (const unsigned short*)&hx[0][0][0];
        #pragma unroll 4
        for (int j = 0; j < H_DIM; ++j) {
            int slot = (j >> 5) * 64 + ((j >> 3) & 3) * 16 + b;
            sum += bf2f(hb[slot * 8 + (j & 7)]) * W_ho[j * O_DIM + o];
        }
        out[(size_t)(r0 + b) * O_DIM + o] = sum;
    }
}

extern "C" void kernel_launch(void* const* d_in, const int* in_sizes, int n_in,
                              void* d_out, int out_size, void* d_ws, size_t ws_size,
                              hipStream_t stream) {
    const float* x    = (const float*)d_in[0];
    const float* W_ih = (const float*)d_in[1];
    const float* b_ih = (const float*)d_in[2];
    const float* W_hh = (const float*)d_in[3];
    const float* b_hh = (const float*)d_in[4];
    const float* W_ho = (const float*)d_in[5];
    const float* b_ho = (const float*)d_in[6];
    const int B = in_sizes[0] / (S_LEN * I_DIM);   // 4096
    rnn_fused<<<B / BT, 256, 0, stream>>>(x, W_ih, b_ih, W_hh, b_hh, W_ho, b_ho,
                                          (float*)d_out);
}